// Round 8
// baseline (5033.823 us; speedup 1.0000x reference)
//
#include <hip/hip_runtime.h>
#include <hip/hip_bf16.h>

typedef __hip_bfloat16 bf16;
typedef unsigned short u16;

static __device__ __forceinline__ bf16 f2b(float x) { return __float2bfloat16(x); }
// bf16 bits -> f32 (exact)
static __device__ __forceinline__ float lo16(unsigned u) { return __uint_as_float(u << 16); }
static __device__ __forceinline__ float hi16(unsigned u) { return __uint_as_float(u & 0xFFFF0000u); }
// f32 -> bf16 bits, round-to-nearest-even (no NaNs in this pipeline)
static __device__ __forceinline__ unsigned f2u(float x) {
    unsigned u = __float_as_uint(x);
    return (u + 0x7FFFu + ((u >> 16) & 1u)) >> 16;
}
static __device__ __forceinline__ unsigned pack2(float a, float b) {
    return f2u(a) | (f2u(b) << 16);
}

// ---- problem constants ----
constexpr int D0 = 240, H0 = 144, W0 = 240;
constexpr int V  = D0 * H0 * W0;          // 8,294,400 voxels
constexpr int NPIX = 480 * 640;           // 307,200 pixels
constexpr int D1 = 120, H1 = 72, W1 = 120;
constexpr int N1 = D1 * H1 * W1;          // 1,036,800
constexpr int D2 = 60, H2 = 36, W2 = 60;
constexpr int N2 = D2 * H2 * W2;          // 129,600

// Volume layout: 3 groups x [V][4] bf16 (channel ci = 4*g + c)
constexpr size_t GRP_U16  = (size_t)V * 4;                    // u16 per group
constexpr size_t SEG_BYTES = 3 * GRP_U16 * sizeof(u16);       // 199,065,600
constexpr size_t WIN_BYTES = (size_t)V * sizeof(unsigned);    // 33,177,600
constexpr int ZCHUNKS = (int)((SEG_BYTES + WIN_BYTES) / 16);  // 14,515,200 uint4
// Workspace peak: SEG_BYTES + 66,355,200 = 265,420,800 bytes — proven safe.

// ============================================================
// Zero-fill (uint4)
// ============================================================
__global__ void __launch_bounds__(256) kz_zero16(uint4* __restrict__ p, int nchunks) {
    int i = blockIdx.x * 256 + threadIdx.x;
    if (i >= nchunks) return;
    p[i] = make_uint4(0u, 0u, 0u, 0u);
}

// ============================================================
// Scatter: last-write-wins via winner = max(pixel_index+1)
// ============================================================
__global__ void __launch_bounds__(256) kz_scatter_win(const int* __restrict__ depth,
                                                      unsigned* __restrict__ winner) {
    int p = blockIdx.x * 256 + threadIdx.x;
    if (p >= NPIX) return;
    int d = depth[p];
    if (d > 0 && d < V) atomicMax(&winner[d], (unsigned)(p + 1));
}

__global__ void __launch_bounds__(256) kz_scatter_write(const int* __restrict__ depth,
                                                        const unsigned* __restrict__ winner,
                                                        const float* __restrict__ feat,
                                                        u16* __restrict__ seg) {
    int p = blockIdx.x * 256 + threadIdx.x;
    if (p >= NPIX) return;
    int d = depth[p];
    if (d > 0 && d < V && winner[d] == (unsigned)(p + 1)) {
#pragma unroll
        for (int g = 0; g < 3; ++g) {
            uint2 val;
            val.x = pack2(feat[(4 * g + 0) * NPIX + p], feat[(4 * g + 1) * NPIX + p]);
            val.y = pack2(feat[(4 * g + 2) * NPIX + p], feat[(4 * g + 3) * NPIX + p]);
            *(uint2*)(seg + g * GRP_U16 + (size_t)d * 4) = val;
        }
    }
}

// ============================================================
// Fill pass A (one group [V][4]): 3-tap W sums -> bf16 tmp, 2 voxels/thread
// ============================================================
__global__ void __launch_bounds__(256) kz_sumwI(const u16* __restrict__ sb,
                                                u16* __restrict__ tb) {
    int r = blockIdx.x * 256 + threadIdx.x;      // grid exact: V/2/256
    int i = 2 * r;                                // even voxel index
    int w = i % W0;                               // even
    uint4 X = *(const uint4*)(sb + (size_t)i * 4);
    float x0[4] = {lo16(X.x), hi16(X.x), lo16(X.y), hi16(X.y)};
    float x1[4] = {lo16(X.z), hi16(X.z), lo16(X.w), hi16(X.w)};
    float l[4] = {0.f, 0.f, 0.f, 0.f}, rr[4] = {0.f, 0.f, 0.f, 0.f};
    if (w > 0) {
        uint2 L = *(const uint2*)(sb + (size_t)(i - 1) * 4);
        l[0] = lo16(L.x); l[1] = hi16(L.x); l[2] = lo16(L.y); l[3] = hi16(L.y);
    }
    if (w < 238) {
        uint2 R = *(const uint2*)(sb + (size_t)(i + 2) * 4);
        rr[0] = lo16(R.x); rr[1] = hi16(R.x); rr[2] = lo16(R.y); rr[3] = hi16(R.y);
    }
    uint4 O;
    O.x = pack2(l[0] + x0[0] + x1[0], l[1] + x0[1] + x1[1]);
    O.y = pack2(l[2] + x0[2] + x1[2], l[3] + x0[3] + x1[3]);
    O.z = pack2(x0[0] + x1[0] + rr[0], x0[1] + x1[1] + rr[1]);
    O.w = pack2(x0[2] + x1[2] + rr[2], x0[3] + x1[3] + rr[3]);
    *(uint4*)(tb + (size_t)i * 4) = O;
}

// ============================================================
// Fill pass B (one group, IN-PLACE): 9-tap (d,h) sum of W row-sums, /27,
// only where raw==0. 2 voxels/thread, 16B accesses.
// ============================================================
__global__ void __launch_bounds__(256) kz_fillI(u16* __restrict__ rb,
                                                const u16* __restrict__ tb) {
    int r = blockIdx.x * 256 + threadIdx.x;
    int i = 2 * r;
    uint4 R = *(const uint4*)(rb + (size_t)i * 4);
    // per-lane bf16 zero test (+0 or -0)
    bool z[8];
    z[0] = (R.x & 0x7FFFu) == 0;          z[1] = ((R.x >> 16) & 0x7FFFu) == 0;
    z[2] = (R.y & 0x7FFFu) == 0;          z[3] = ((R.y >> 16) & 0x7FFFu) == 0;
    z[4] = (R.z & 0x7FFFu) == 0;          z[5] = ((R.z >> 16) & 0x7FFFu) == 0;
    z[6] = (R.w & 0x7FFFu) == 0;          z[7] = ((R.w >> 16) & 0x7FFFu) == 0;
    if (!(z[0] | z[1] | z[2] | z[3] | z[4] | z[5] | z[6] | z[7])) return;
    int w = i % W0;
    int t = i / W0;
    int h = t % H0;
    int d = t / H0;
    float s[8] = {0.f, 0.f, 0.f, 0.f, 0.f, 0.f, 0.f, 0.f};
#pragma unroll
    for (int dd = -1; dd <= 1; ++dd) {
        int d2 = d + dd;
        if (d2 < 0 || d2 >= D0) continue;
#pragma unroll
        for (int dh = -1; dh <= 1; ++dh) {
            int h2 = h + dh;
            if (h2 < 0 || h2 >= H0) continue;
            uint4 T = *(const uint4*)(tb + (size_t)((d2 * H0 + h2) * W0 + w) * 4);
            s[0] += lo16(T.x); s[1] += hi16(T.x); s[2] += lo16(T.y); s[3] += hi16(T.y);
            s[4] += lo16(T.z); s[5] += hi16(T.z); s[6] += lo16(T.w); s[7] += hi16(T.w);
        }
    }
    constexpr float inv27 = 1.0f / 27.0f;
    uint4 O;
    O.x = (z[0] ? f2u(s[0] * inv27) : (R.x & 0xFFFFu)) | ((z[1] ? f2u(s[1] * inv27) : (R.x >> 16)) << 16);
    O.y = (z[2] ? f2u(s[2] * inv27) : (R.y & 0xFFFFu)) | ((z[3] ? f2u(s[3] * inv27) : (R.y >> 16)) << 16);
    O.z = (z[4] ? f2u(s[4] * inv27) : (R.z & 0xFFFFu)) | ((z[5] ? f2u(s[5] * inv27) : (R.z >> 16)) << 16);
    O.w = (z[6] ? f2u(s[6] * inv27) : (R.w & 0xFFFFu)) | ((z[7] ? f2u(s[7] * inv27) : (R.w >> 16)) << 16);
    *(uint4*)(rb + (size_t)i * 4) = O;
}

// ============================================================
// Downsample 1: conv3d 12->4 (k3,s2,p1) ++ maxpool2 of 12ch, relu
// interleaved bf16 volume in, f32 weights, f32 out [16][N1]
// ============================================================
__global__ void __launch_bounds__(256) kz_ds1(const u16* __restrict__ seg,
                                              const float* __restrict__ w,
                                              float* __restrict__ out) {
    __shared__ float wl[4 * 12 * 27];
    for (int t = threadIdx.x; t < 4 * 12 * 27; t += 256) wl[t] = w[t];
    __syncthreads();
    int o = blockIdx.x * 256 + threadIdx.x;
    if (o >= N1) return;
    int wo = o % W1;
    int t  = o / W1;
    int ho = t % H1;
    int d0 = t / H1;
    float acc[4] = {0.f, 0.f, 0.f, 0.f};
#pragma unroll
    for (int g = 0; g < 3; ++g) {
        const u16* base = seg + g * GRP_U16;
        float mxg[4] = {-1e30f, -1e30f, -1e30f, -1e30f};
#pragma unroll
        for (int kd = 0; kd < 3; ++kd) {
            int d2 = 2 * d0 - 1 + kd;
            bool dv = (d2 >= 0 && d2 < D0);
#pragma unroll
            for (int kh = 0; kh < 3; ++kh) {
                int h2 = 2 * ho - 1 + kh;
                bool rvv = dv && (h2 >= 0 && h2 < H0);
                float vm1[4] = {0.f, 0.f, 0.f, 0.f};
                float v0[4]  = {0.f, 0.f, 0.f, 0.f};
                float v1[4]  = {0.f, 0.f, 0.f, 0.f};
                if (rvv) {
                    size_t r2 = (size_t)((d2 * H0 + h2) * W0 + 2 * wo);
                    uint2 A = *(const uint2*)(base + r2 * 4);            // w2 = 2wo
                    uint2 B = *(const uint2*)(base + (r2 + 1) * 4);      // w2 = 2wo+1
                    v0[0] = lo16(A.x); v0[1] = hi16(A.x); v0[2] = lo16(A.y); v0[3] = hi16(A.y);
                    v1[0] = lo16(B.x); v1[1] = hi16(B.x); v1[2] = lo16(B.y); v1[3] = hi16(B.y);
                    if (wo > 0) {
                        uint2 Cc = *(const uint2*)(base + (r2 - 1) * 4); // w2 = 2wo-1
                        vm1[0] = lo16(Cc.x); vm1[1] = hi16(Cc.x); vm1[2] = lo16(Cc.y); vm1[3] = hi16(Cc.y);
                    }
                }
                const float* wg = wl + (4 * g) * 27 + kd * 9 + kh * 3;
#pragma unroll
                for (int m = 0; m < 4; ++m) {
                    const float* wm = wg + m * 324;
#pragma unroll
                    for (int c = 0; c < 4; ++c)
                        acc[m] += vm1[c] * wm[c * 27] + v0[c] * wm[c * 27 + 1] + v1[c] * wm[c * 27 + 2];
                }
                if (kd >= 1 && kh >= 1) {
#pragma unroll
                    for (int c = 0; c < 4; ++c)
                        mxg[c] = fmaxf(mxg[c], fmaxf(v0[c], v1[c]));   // pool = inner 2x2x2
                }
            }
        }
#pragma unroll
        for (int c = 0; c < 4; ++c)
            out[(4 + 4 * g + c) * N1 + o] = fmaxf(mxg[c], 0.f);
    }
#pragma unroll
    for (int m = 0; m < 4; ++m) out[m * N1 + o] = fmaxf(acc[m], 0.f);
}

// ============================================================
// Downsample 2: conv3d 16->16 (k3,s2,p1) ++ maxpool2 of 16ch, relu
// f32 in/out. Paired W loads (float2).
// ============================================================
__global__ void __launch_bounds__(256) kz_ds2(const float* __restrict__ in,
                                              const float* __restrict__ w,
                                              float* __restrict__ out) {
    __shared__ float wl[16 * 16 * 27];
    for (int t = threadIdx.x; t < 16 * 16 * 27; t += 256) wl[t] = w[t];
    __syncthreads();
    int o = blockIdx.x * 256 + threadIdx.x;
    if (o >= N2) return;
    int wo = o % W2;
    int t  = o / W2;
    int ho = t % H2;
    int d0 = t / H2;
    float acc[16];
#pragma unroll
    for (int m = 0; m < 16; ++m) acc[m] = 0.f;
    for (int ci = 0; ci < 16; ++ci) {
        const float* base = in + ci * N1;
        const float* wci = wl + ci * 27;
        float mx = -1e30f;
#pragma unroll
        for (int kd = 0; kd < 3; ++kd) {
            int d2 = 2 * d0 - 1 + kd;
            bool dv = (d2 >= 0 && d2 < D1);
#pragma unroll
            for (int kh = 0; kh < 3; ++kh) {
                int h2 = 2 * ho - 1 + kh;
                bool rvv = dv && (h2 >= 0 && h2 < H1);
                float vm1 = 0.f, v0 = 0.f, v1 = 0.f;
                if (rvv) {
                    int r2 = (d2 * H1 + h2) * W1 + 2 * wo;
                    float2 pb = *(const float2*)(base + r2);
                    v0 = pb.x; v1 = pb.y;
                    if (wo > 0) {
                        float2 pa = *(const float2*)(base + r2 - 2);
                        vm1 = pa.y;
                    }
                }
                const float* wk = wci + kd * 9 + kh * 3;
#pragma unroll
                for (int m = 0; m < 16; ++m)
                    acc[m] += vm1 * wk[m * 432] + v0 * wk[m * 432 + 1] + v1 * wk[m * 432 + 2];
                if (kd >= 1 && kh >= 1) mx = fmaxf(mx, fmaxf(v0, v1));
            }
        }
        out[(16 + ci) * N2 + o] = fmaxf(mx, 0.f);
    }
#pragma unroll
    for (int m = 0; m < 16; ++m) out[m * N2 + o] = fmaxf(acc[m], 0.f);
}

// ============================================================
// Pointwise (1x1x1) conv, optional residual, relu, f32 out
// ============================================================
template <int CIN, int COUT, bool HASRES>
__global__ void __launch_bounds__(256) kz_pw(const float* __restrict__ in,
                                             const float* __restrict__ w,
                                             const float* __restrict__ res,
                                             float* __restrict__ outf, int N) {
    __shared__ float wl[CIN * COUT];
    for (int t = threadIdx.x; t < CIN * COUT; t += 256) wl[t] = w[t];
    __syncthreads();
    int o = blockIdx.x * 256 + threadIdx.x;
    if (o >= N) return;
    float acc[COUT];
#pragma unroll
    for (int m = 0; m < COUT; ++m) acc[m] = 0.f;
    for (int ci = 0; ci < CIN; ++ci) {
        float v = in[ci * N + o];
#pragma unroll
        for (int m = 0; m < COUT; ++m) acc[m] += v * wl[m * CIN + ci];
    }
#pragma unroll
    for (int m = 0; m < COUT; ++m) {
        float r = acc[m];
        if (HASRES) r += res[m * N + o];
        outf[m * N + o] = fmaxf(r, 0.f);
    }
}

// ============================================================
// Bottleneck middle conv: C->C, kernel (KD,KH,KW) same-pad on >1 dims,
// + bias + up to 2 residual adds + relu. f32 in/out.
// ============================================================
template <int C, int KD, int KH, int KW, int NADD>
__global__ void __launch_bounds__(256) kz_bconv(const float* __restrict__ in,
                                                const float* __restrict__ w,
                                                const float* __restrict__ b,
                                                const float* __restrict__ add1,
                                                const float* __restrict__ add2,
                                                float* __restrict__ out,
                                                int Dd, int Hh, int Ww, int N) {
    __shared__ float wl[C * C * KD * KH * KW];
    __shared__ float bl[C];
    for (int t = threadIdx.x; t < C * C * KD * KH * KW; t += 256) wl[t] = w[t];
    if (threadIdx.x < C) bl[threadIdx.x] = b[threadIdx.x];
    __syncthreads();
    int o = blockIdx.x * 256 + threadIdx.x;
    if (o >= N) return;
    int wo = o % Ww;
    int t  = o / Ww;
    int ho = t % Hh;
    int d0 = t / Hh;
    float acc[C];
#pragma unroll
    for (int m = 0; m < C; ++m) acc[m] = bl[m];
    for (int ci = 0; ci < C; ++ci) {
        const float* base = in + ci * N;
        const float* wci = wl + ci * KD * KH * KW;
#pragma unroll
        for (int kd = 0; kd < KD; ++kd) {
            int d2 = d0 + kd - KD / 2;
            if (d2 < 0 || d2 >= Dd) continue;
#pragma unroll
            for (int kh = 0; kh < KH; ++kh) {
                int h2 = ho + kh - KH / 2;
                if (h2 < 0 || h2 >= Hh) continue;
#pragma unroll
                for (int kw = 0; kw < KW; ++kw) {
                    int w2 = wo + kw - KW / 2;
                    if (w2 < 0 || w2 >= Ww) continue;
                    float v = base[(d2 * Hh + h2) * Ww + w2];
                    int wi = kd * KH * KW + kh * KW + kw;
#pragma unroll
                    for (int m = 0; m < C; ++m)
                        acc[m] += v * wci[m * C * KD * KH * KW + wi];
                }
            }
        }
    }
#pragma unroll
    for (int m = 0; m < C; ++m) {
        float r = acc[m];
        if (NADD >= 1) r += add1[m * N + o];
        if (NADD >= 2) r += add2[m * N + o];
        out[m * N + o] = fmaxf(r, 0.f);
    }
}

// ============================================================
extern "C" void kernel_launch(void* const* d_in, const int* in_sizes, int n_in,
                              void* d_out, int out_size, void* d_ws, size_t ws_size,
                              hipStream_t stream) {
    const float* feat   = (const float*)d_in[0];
    const int*   depth  = (const int*)d_in[1];
    const float* w_ds1  = (const float*)d_in[2];
    const float* b1_win = (const float*)d_in[3];
    const float* b1w133 = (const float*)d_in[4];
    const float* b1b133 = (const float*)d_in[5];
    const float* b1w331 = (const float*)d_in[6];
    const float* b1b331 = (const float*)d_in[7];
    const float* b1w313 = (const float*)d_in[8];
    const float* b1b313 = (const float*)d_in[9];
    const float* b1wout = (const float*)d_in[10];
    const float* w_ds2  = (const float*)d_in[11];
    const float* b2_win = (const float*)d_in[12];
    const float* b2w133 = (const float*)d_in[13];
    const float* b2b133 = (const float*)d_in[14];
    const float* b2w331 = (const float*)d_in[15];
    const float* b2b331 = (const float*)d_in[16];
    const float* b2w313 = (const float*)d_in[17];
    const float* b2b313 = (const float*)d_in[18];
    const float* b2wout = (const float*)d_in[19];

    char* base = (char*)d_ws;

    // --- Region layout (time-shared; peak = SEG_BYTES + 66.4MB = 265.4 MB) ---
    u16* segu = (u16*)base;                               // [0, SEG): 3 groups x [V][4] bf16
    unsigned* winner = (unsigned*)(base + SEG_BYTES);     // [SEG, SEG+33.2MB)
    u16*      tmpu   = (u16*)(base + SEG_BYTES);          // bf16[V][4] = 66.4MB, after winner dies
    float*    x1     = (float*)(base + SEG_BYTES);        // 16*N1 f32 = 66.4MB, after tmp dies
    float* y0  = (float*)base;                            // after seg dies: 4*N1 f32 each
    float* y1  = y0 + 4 * N1;
    float* y2  = y1 + 4 * N1;
    float* y3  = y2 + 4 * N1;
    float* x1b = (float*)base + 16 * N1;                  // [66.4MB, 132.8MB)
    float* x2 = (float*)base;                             // after y dead: 32*N2 f32
    float* z0 = x2 + 32 * N2;
    float* z1 = z0 + 8 * N2;
    float* z2 = z1 + 8 * N2;
    float* z3 = z2 + 8 * N2;                              // ends at 33.2MB < x1b start

    float* out = (float*)d_out;   // reference output dtype is float32

    // 1. zero volume + winner (contiguous)
    kz_zero16<<<ZCHUNKS / 256, 256, 0, stream>>>((uint4*)base, ZCHUNKS);

    // 2. deterministic last-write-wins scatter
    kz_scatter_win  <<<NPIX / 256, 256, 0, stream>>>(depth, winner);
    kz_scatter_write<<<NPIX / 256, 256, 0, stream>>>(depth, winner, feat, segu);

    // 3. avg-pool hole-fill, separable, per 4-ch group, in-place
    for (int g = 0; g < 3; ++g) {
        u16* gb = segu + (size_t)g * GRP_U16;
        kz_sumwI<<<(V / 2) / 256, 256, 0, stream>>>(gb, tmpu);
        kz_fillI<<<(V / 2) / 256, 256, 0, stream>>>(gb, tmpu);
    }

    // 4. downsample 1 -> x1 f32 [16][N1]
    kz_ds1<<<N1 / 256, 256, 0, stream>>>(segu, w_ds1, x1);

    // 5. bottleneck 1 (ch16, mid4, spatial 120x72x120)
    kz_pw<16, 4, false><<<N1 / 256, 256, 0, stream>>>(x1, b1_win, nullptr, y0, N1);
    kz_bconv<4, 1, 3, 3, 0><<<N1 / 256, 256, 0, stream>>>(y0, b1w133, b1b133, nullptr, nullptr, y1, D1, H1, W1, N1);
    kz_bconv<4, 3, 3, 1, 1><<<N1 / 256, 256, 0, stream>>>(y1, b1w331, b1b331, y1, nullptr, y2, D1, H1, W1, N1);
    kz_bconv<4, 3, 1, 3, 2><<<N1 / 256, 256, 0, stream>>>(y2, b1w313, b1b313, y2, y1, y3, D1, H1, W1, N1);
    kz_pw<4, 16, true><<<N1 / 256, 256, 0, stream>>>(y3, b1wout, x1, x1b, N1);

    // 6. downsample 2 -> x2 f32 [32][N2]
    kz_ds2<<<(N2 + 255) / 256, 256, 0, stream>>>(x1b, w_ds2, x2);

    // 7. bottleneck 2 (ch32, mid8, spatial 60x36x60) -> f32 d_out
    kz_pw<32, 8, false><<<(N2 + 255) / 256, 256, 0, stream>>>(x2, b2_win, nullptr, z0, N2);
    kz_bconv<8, 1, 3, 3, 0><<<(N2 + 255) / 256, 256, 0, stream>>>(z0, b2w133, b2b133, nullptr, nullptr, z1, D2, H2, W2, N2);
    kz_bconv<8, 3, 3, 1, 1><<<(N2 + 255) / 256, 256, 0, stream>>>(z1, b2w331, b2b331, z1, nullptr, z2, D2, H2, W2, N2);
    kz_bconv<8, 3, 1, 3, 2><<<(N2 + 255) / 256, 256, 0, stream>>>(z2, b2w313, b2b313, z2, z1, z3, D2, H2, W2, N2);
    kz_pw<8, 32, true><<<(N2 + 255) / 256, 256, 0, stream>>>(z3, b2wout, x2, out, N2);

    (void)in_sizes; (void)n_in; (void)out_size; (void)ws_size;
}

// Round 9
// 906.798 us; speedup vs baseline: 5.5512x; 5.5512x over previous
//
#include <hip/hip_runtime.h>
#include <hip/hip_bf16.h>

typedef __hip_bfloat16 bf16;
typedef unsigned short u16;

static __device__ __forceinline__ bf16 f2b(float x) { return __float2bfloat16(x); }
// bf16 bits -> f32 (exact)
static __device__ __forceinline__ float lo16(unsigned u) { return __uint_as_float(u << 16); }
static __device__ __forceinline__ float hi16(unsigned u) { return __uint_as_float(u & 0xFFFF0000u); }
// f32 -> bf16 bits, round-to-nearest-even (no NaNs in this pipeline)
static __device__ __forceinline__ unsigned f2u(float x) {
    unsigned u = __float_as_uint(x);
    return (u + 0x7FFFu + ((u >> 16) & 1u)) >> 16;
}
static __device__ __forceinline__ unsigned pack2(float a, float b) {
    return f2u(a) | (f2u(b) << 16);
}

// ---- problem constants ----
constexpr int D0 = 240, H0 = 144, W0 = 240;
constexpr int V  = D0 * H0 * W0;          // 8,294,400 voxels
constexpr int NPIX = 480 * 640;           // 307,200 pixels
constexpr int D1 = 120, H1 = 72, W1 = 120;
constexpr int N1 = D1 * H1 * W1;          // 1,036,800
constexpr int D2 = 60, H2 = 36, W2 = 60;
constexpr int N2 = D2 * H2 * W2;          // 129,600

// Volume layout: 3 groups x [V][4] bf16 (channel ci = 4*g + c)
constexpr size_t GRP_U16  = (size_t)V * 4;                    // u16 per group
constexpr size_t SEG_BYTES = 3 * GRP_U16 * sizeof(u16);       // 199,065,600
constexpr size_t WIN_BYTES = (size_t)V * sizeof(unsigned);    // 33,177,600
constexpr int ZCHUNKS = (int)((SEG_BYTES + WIN_BYTES) / 16);  // 14,515,200 uint4
// Workspace peak: SEG_BYTES + 66,355,200 = 265,420,800 bytes — proven safe.

// ============================================================
// Zero-fill (uint4)
// ============================================================
__global__ void __launch_bounds__(256) kz_zero16(uint4* __restrict__ p, int nchunks) {
    int i = blockIdx.x * 256 + threadIdx.x;
    if (i >= nchunks) return;
    p[i] = make_uint4(0u, 0u, 0u, 0u);
}

// ============================================================
// Scatter: last-write-wins via winner = max(pixel_index+1)
// ============================================================
__global__ void __launch_bounds__(256) kz_scatter_win(const int* __restrict__ depth,
                                                      unsigned* __restrict__ winner) {
    int p = blockIdx.x * 256 + threadIdx.x;
    if (p >= NPIX) return;
    int d = depth[p];
    if (d > 0 && d < V) atomicMax(&winner[d], (unsigned)(p + 1));
}

__global__ void __launch_bounds__(256) kz_scatter_write(const int* __restrict__ depth,
                                                        const unsigned* __restrict__ winner,
                                                        const float* __restrict__ feat,
                                                        u16* __restrict__ seg) {
    int p = blockIdx.x * 256 + threadIdx.x;
    if (p >= NPIX) return;
    int d = depth[p];
    if (d > 0 && d < V && winner[d] == (unsigned)(p + 1)) {
#pragma unroll
        for (int g = 0; g < 3; ++g) {
            uint2 val;
            val.x = pack2(feat[(4 * g + 0) * NPIX + p], feat[(4 * g + 1) * NPIX + p]);
            val.y = pack2(feat[(4 * g + 2) * NPIX + p], feat[(4 * g + 3) * NPIX + p]);
            *(uint2*)(seg + g * GRP_U16 + (size_t)d * 4) = val;
        }
    }
}

// ============================================================
// Fill pass A (one group [V][4]): 3-tap W sums -> bf16 tmp, 2 voxels/thread
// ============================================================
__global__ void __launch_bounds__(256) kz_sumwI(const u16* __restrict__ sb,
                                                u16* __restrict__ tb) {
    int r = blockIdx.x * 256 + threadIdx.x;      // grid exact: V/2/256
    int i = 2 * r;                                // even voxel index
    int w = i % W0;                               // even
    uint4 X = *(const uint4*)(sb + (size_t)i * 4);
    float x0[4] = {lo16(X.x), hi16(X.x), lo16(X.y), hi16(X.y)};
    float x1[4] = {lo16(X.z), hi16(X.z), lo16(X.w), hi16(X.w)};
    float l[4] = {0.f, 0.f, 0.f, 0.f}, rr[4] = {0.f, 0.f, 0.f, 0.f};
    if (w > 0) {
        uint2 L = *(const uint2*)(sb + (size_t)(i - 1) * 4);
        l[0] = lo16(L.x); l[1] = hi16(L.x); l[2] = lo16(L.y); l[3] = hi16(L.y);
    }
    if (w < 238) {
        uint2 R = *(const uint2*)(sb + (size_t)(i + 2) * 4);
        rr[0] = lo16(R.x); rr[1] = hi16(R.x); rr[2] = lo16(R.y); rr[3] = hi16(R.y);
    }
    uint4 O;
    O.x = pack2(l[0] + x0[0] + x1[0], l[1] + x0[1] + x1[1]);
    O.y = pack2(l[2] + x0[2] + x1[2], l[3] + x0[3] + x1[3]);
    O.z = pack2(x0[0] + x1[0] + rr[0], x0[1] + x1[1] + rr[1]);
    O.w = pack2(x0[2] + x1[2] + rr[2], x0[3] + x1[3] + rr[3]);
    *(uint4*)(tb + (size_t)i * 4) = O;
}

// ============================================================
// Fill pass B (one group, IN-PLACE): 9-tap (d,h) sum of W row-sums, /27,
// only where raw==0. 2 voxels/thread, 16B accesses.
// ============================================================
__global__ void __launch_bounds__(256) kz_fillI(u16* __restrict__ rb,
                                                const u16* __restrict__ tb) {
    int r = blockIdx.x * 256 + threadIdx.x;
    int i = 2 * r;
    uint4 R = *(const uint4*)(rb + (size_t)i * 4);
    // per-lane bf16 zero test (+0 or -0)
    bool z[8];
    z[0] = (R.x & 0x7FFFu) == 0;          z[1] = ((R.x >> 16) & 0x7FFFu) == 0;
    z[2] = (R.y & 0x7FFFu) == 0;          z[3] = ((R.y >> 16) & 0x7FFFu) == 0;
    z[4] = (R.z & 0x7FFFu) == 0;          z[5] = ((R.z >> 16) & 0x7FFFu) == 0;
    z[6] = (R.w & 0x7FFFu) == 0;          z[7] = ((R.w >> 16) & 0x7FFFu) == 0;
    if (!(z[0] | z[1] | z[2] | z[3] | z[4] | z[5] | z[6] | z[7])) return;
    int w = i % W0;
    int t = i / W0;
    int h = t % H0;
    int d = t / H0;
    float s[8] = {0.f, 0.f, 0.f, 0.f, 0.f, 0.f, 0.f, 0.f};
#pragma unroll
    for (int dd = -1; dd <= 1; ++dd) {
        int d2 = d + dd;
        if (d2 < 0 || d2 >= D0) continue;
#pragma unroll
        for (int dh = -1; dh <= 1; ++dh) {
            int h2 = h + dh;
            if (h2 < 0 || h2 >= H0) continue;
            uint4 T = *(const uint4*)(tb + (size_t)((d2 * H0 + h2) * W0 + w) * 4);
            s[0] += lo16(T.x); s[1] += hi16(T.x); s[2] += lo16(T.y); s[3] += hi16(T.y);
            s[4] += lo16(T.z); s[5] += hi16(T.z); s[6] += lo16(T.w); s[7] += hi16(T.w);
        }
    }
    constexpr float inv27 = 1.0f / 27.0f;
    uint4 O;
    O.x = (z[0] ? f2u(s[0] * inv27) : (R.x & 0xFFFFu)) | ((z[1] ? f2u(s[1] * inv27) : (R.x >> 16)) << 16);
    O.y = (z[2] ? f2u(s[2] * inv27) : (R.y & 0xFFFFu)) | ((z[3] ? f2u(s[3] * inv27) : (R.y >> 16)) << 16);
    O.z = (z[4] ? f2u(s[4] * inv27) : (R.z & 0xFFFFu)) | ((z[5] ? f2u(s[5] * inv27) : (R.z >> 16)) << 16);
    O.w = (z[6] ? f2u(s[6] * inv27) : (R.w & 0xFFFFu)) | ((z[7] ? f2u(s[7] * inv27) : (R.w >> 16)) << 16);
    *(uint4*)(rb + (size_t)i * 4) = O;
}

// ============================================================
// Downsample 1: conv3d 12->4 (k3,s2,p1) ++ maxpool2 of 12ch, relu
// interleaved bf16 volume in, f32 weights, f32 out [16][N1]
// Register-pressure-controlled: g and kd loops NOT unrolled (R8 spilled).
// ============================================================
__global__ void __launch_bounds__(256) kz_ds1(const u16* __restrict__ seg,
                                              const float* __restrict__ w,
                                              float* __restrict__ out) {
    __shared__ float wl[4 * 12 * 27];
    for (int t = threadIdx.x; t < 4 * 12 * 27; t += 256) wl[t] = w[t];
    __syncthreads();
    int o = blockIdx.x * 256 + threadIdx.x;
    if (o >= N1) return;
    int wo = o % W1;
    int t  = o / W1;
    int ho = t % H1;
    int d0 = t / H1;
    float acc[4] = {0.f, 0.f, 0.f, 0.f};
#pragma unroll 1
    for (int g = 0; g < 3; ++g) {
        const u16* base = seg + (size_t)g * GRP_U16;
        const float* wg = wl + (4 * g) * 27;      // + m*324 + c*27 + kd*9 + kh*3 + kw
        float mx0 = -1e30f, mx1 = -1e30f, mx2 = -1e30f, mx3 = -1e30f;
#pragma unroll 1
        for (int kd = 0; kd < 3; ++kd) {
            int d2 = 2 * d0 - 1 + kd;
            bool dv = (d2 >= 0 && d2 < D0);
#pragma unroll
            for (int kh = 0; kh < 3; ++kh) {
                int h2 = 2 * ho - 1 + kh;
                bool rvv = dv && (h2 >= 0 && h2 < H0);
                float a0 = 0.f, a1 = 0.f, a2 = 0.f, a3 = 0.f;   // w2 = 2wo-1
                float b0 = 0.f, b1 = 0.f, b2 = 0.f, b3 = 0.f;   // w2 = 2wo
                float c0 = 0.f, c1 = 0.f, c2 = 0.f, c3 = 0.f;   // w2 = 2wo+1
                if (rvv) {
                    size_t r2 = (size_t)((d2 * H0 + h2) * W0 + 2 * wo);
                    uint4 AB = *(const uint4*)(base + r2 * 4);   // 16B: voxels 2wo, 2wo+1 (r2 even)
                    b0 = lo16(AB.x); b1 = hi16(AB.x); b2 = lo16(AB.y); b3 = hi16(AB.y);
                    c0 = lo16(AB.z); c1 = hi16(AB.z); c2 = lo16(AB.w); c3 = hi16(AB.w);
                    if (wo > 0) {
                        uint2 P = *(const uint2*)(base + (r2 - 1) * 4);
                        a0 = lo16(P.x); a1 = hi16(P.x); a2 = lo16(P.y); a3 = hi16(P.y);
                    }
                }
                const float* wk = wg + kd * 9 + kh * 3;
#pragma unroll
                for (int m = 0; m < 4; ++m) {
                    const float* wm = wk + m * 324;
                    acc[m] += a0 * wm[0]  + b0 * wm[1]  + c0 * wm[2]
                            + a1 * wm[27] + b1 * wm[28] + c1 * wm[29]
                            + a2 * wm[54] + b2 * wm[55] + c2 * wm[56]
                            + a3 * wm[81] + b3 * wm[82] + c3 * wm[83];
                }
                if (kd >= 1 && kh >= 1) {        // pool = inner 2x2x2
                    mx0 = fmaxf(mx0, fmaxf(b0, c0));
                    mx1 = fmaxf(mx1, fmaxf(b1, c1));
                    mx2 = fmaxf(mx2, fmaxf(b2, c2));
                    mx3 = fmaxf(mx3, fmaxf(b3, c3));
                }
            }
        }
        out[(4 + 4 * g + 0) * N1 + o] = fmaxf(mx0, 0.f);
        out[(4 + 4 * g + 1) * N1 + o] = fmaxf(mx1, 0.f);
        out[(4 + 4 * g + 2) * N1 + o] = fmaxf(mx2, 0.f);
        out[(4 + 4 * g + 3) * N1 + o] = fmaxf(mx3, 0.f);
    }
#pragma unroll
    for (int m = 0; m < 4; ++m) out[m * N1 + o] = fmaxf(acc[m], 0.f);
}

// ============================================================
// Downsample 2: conv3d 16->16 (k3,s2,p1) ++ maxpool2 of 16ch, relu
// f32 in/out. Paired W loads (float2).
// ============================================================
__global__ void __launch_bounds__(256) kz_ds2(const float* __restrict__ in,
                                              const float* __restrict__ w,
                                              float* __restrict__ out) {
    __shared__ float wl[16 * 16 * 27];
    for (int t = threadIdx.x; t < 16 * 16 * 27; t += 256) wl[t] = w[t];
    __syncthreads();
    int o = blockIdx.x * 256 + threadIdx.x;
    if (o >= N2) return;
    int wo = o % W2;
    int t  = o / W2;
    int ho = t % H2;
    int d0 = t / H2;
    float acc[16];
#pragma unroll
    for (int m = 0; m < 16; ++m) acc[m] = 0.f;
#pragma unroll 1
    for (int ci = 0; ci < 16; ++ci) {
        const float* base = in + ci * N1;
        const float* wci = wl + ci * 27;
        float mx = -1e30f;
#pragma unroll 1
        for (int kd = 0; kd < 3; ++kd) {
            int d2 = 2 * d0 - 1 + kd;
            bool dv = (d2 >= 0 && d2 < D1);
#pragma unroll
            for (int kh = 0; kh < 3; ++kh) {
                int h2 = 2 * ho - 1 + kh;
                bool rvv = dv && (h2 >= 0 && h2 < H1);
                float vm1 = 0.f, v0 = 0.f, v1 = 0.f;
                if (rvv) {
                    int r2 = (d2 * H1 + h2) * W1 + 2 * wo;
                    float2 pb = *(const float2*)(base + r2);
                    v0 = pb.x; v1 = pb.y;
                    if (wo > 0) {
                        float2 pa = *(const float2*)(base + r2 - 2);
                        vm1 = pa.y;
                    }
                }
                const float* wk = wci + kd * 9 + kh * 3;
#pragma unroll
                for (int m = 0; m < 16; ++m)
                    acc[m] += vm1 * wk[m * 432] + v0 * wk[m * 432 + 1] + v1 * wk[m * 432 + 2];
                if (kd >= 1 && kh >= 1) mx = fmaxf(mx, fmaxf(v0, v1));
            }
        }
        out[(16 + ci) * N2 + o] = fmaxf(mx, 0.f);
    }
#pragma unroll
    for (int m = 0; m < 16; ++m) out[m * N2 + o] = fmaxf(acc[m], 0.f);
}

// ============================================================
// Pointwise (1x1x1) conv, optional residual, relu, f32 out
// ============================================================
template <int CIN, int COUT, bool HASRES>
__global__ void __launch_bounds__(256) kz_pw(const float* __restrict__ in,
                                             const float* __restrict__ w,
                                             const float* __restrict__ res,
                                             float* __restrict__ outf, int N) {
    __shared__ float wl[CIN * COUT];
    for (int t = threadIdx.x; t < CIN * COUT; t += 256) wl[t] = w[t];
    __syncthreads();
    int o = blockIdx.x * 256 + threadIdx.x;
    if (o >= N) return;
    float acc[COUT];
#pragma unroll
    for (int m = 0; m < COUT; ++m) acc[m] = 0.f;
    for (int ci = 0; ci < CIN; ++ci) {
        float v = in[ci * N + o];
#pragma unroll
        for (int m = 0; m < COUT; ++m) acc[m] += v * wl[m * CIN + ci];
    }
#pragma unroll
    for (int m = 0; m < COUT; ++m) {
        float r = acc[m];
        if (HASRES) r += res[m * N + o];
        outf[m * N + o] = fmaxf(r, 0.f);
    }
}

// ============================================================
// Bottleneck middle conv: C->C, kernel (KD,KH,KW) same-pad on >1 dims,
// + bias + up to 2 residual adds + relu. f32 in/out.
// ============================================================
template <int C, int KD, int KH, int KW, int NADD>
__global__ void __launch_bounds__(256) kz_bconv(const float* __restrict__ in,
                                                const float* __restrict__ w,
                                                const float* __restrict__ b,
                                                const float* __restrict__ add1,
                                                const float* __restrict__ add2,
                                                float* __restrict__ out,
                                                int Dd, int Hh, int Ww, int N) {
    __shared__ float wl[C * C * KD * KH * KW];
    __shared__ float bl[C];
    for (int t = threadIdx.x; t < C * C * KD * KH * KW; t += 256) wl[t] = w[t];
    if (threadIdx.x < C) bl[threadIdx.x] = b[threadIdx.x];
    __syncthreads();
    int o = blockIdx.x * 256 + threadIdx.x;
    if (o >= N) return;
    int wo = o % Ww;
    int t  = o / Ww;
    int ho = t % Hh;
    int d0 = t / Hh;
    float acc[C];
#pragma unroll
    for (int m = 0; m < C; ++m) acc[m] = bl[m];
#pragma unroll 1
    for (int ci = 0; ci < C; ++ci) {
        const float* base = in + ci * N;
        const float* wci = wl + ci * KD * KH * KW;
#pragma unroll
        for (int kd = 0; kd < KD; ++kd) {
            int d2 = d0 + kd - KD / 2;
            if (d2 < 0 || d2 >= Dd) continue;
#pragma unroll
            for (int kh = 0; kh < KH; ++kh) {
                int h2 = ho + kh - KH / 2;
                if (h2 < 0 || h2 >= Hh) continue;
#pragma unroll
                for (int kw = 0; kw < KW; ++kw) {
                    int w2 = wo + kw - KW / 2;
                    if (w2 < 0 || w2 >= Ww) continue;
                    float v = base[(d2 * Hh + h2) * Ww + w2];
                    int wi = kd * KH * KW + kh * KW + kw;
#pragma unroll
                    for (int m = 0; m < C; ++m)
                        acc[m] += v * wci[m * C * KD * KH * KW + wi];
                }
            }
        }
    }
#pragma unroll
    for (int m = 0; m < C; ++m) {
        float r = acc[m];
        if (NADD >= 1) r += add1[m * N + o];
        if (NADD >= 2) r += add2[m * N + o];
        out[m * N + o] = fmaxf(r, 0.f);
    }
}

// ============================================================
extern "C" void kernel_launch(void* const* d_in, const int* in_sizes, int n_in,
                              void* d_out, int out_size, void* d_ws, size_t ws_size,
                              hipStream_t stream) {
    const float* feat   = (const float*)d_in[0];
    const int*   depth  = (const int*)d_in[1];
    const float* w_ds1  = (const float*)d_in[2];
    const float* b1_win = (const float*)d_in[3];
    const float* b1w133 = (const float*)d_in[4];
    const float* b1b133 = (const float*)d_in[5];
    const float* b1w331 = (const float*)d_in[6];
    const float* b1b331 = (const float*)d_in[7];
    const float* b1w313 = (const float*)d_in[8];
    const float* b1b313 = (const float*)d_in[9];
    const float* b1wout = (const float*)d_in[10];
    const float* w_ds2  = (const float*)d_in[11];
    const float* b2_win = (const float*)d_in[12];
    const float* b2w133 = (const float*)d_in[13];
    const float* b2b133 = (const float*)d_in[14];
    const float* b2w331 = (const float*)d_in[15];
    const float* b2b331 = (const float*)d_in[16];
    const float* b2w313 = (const float*)d_in[17];
    const float* b2b313 = (const float*)d_in[18];
    const float* b2wout = (const float*)d_in[19];

    char* base = (char*)d_ws;

    // --- Region layout (time-shared; peak = SEG_BYTES + 66.4MB = 265.4 MB) ---
    u16* segu = (u16*)base;                               // [0, SEG): 3 groups x [V][4] bf16
    unsigned* winner = (unsigned*)(base + SEG_BYTES);     // [SEG, SEG+33.2MB)
    u16*      tmpu   = (u16*)(base + SEG_BYTES);          // bf16[V][4] = 66.4MB, after winner dies
    float*    x1     = (float*)(base + SEG_BYTES);        // 16*N1 f32 = 66.4MB, after tmp dies
    float* y0  = (float*)base;                            // after seg dies: 4*N1 f32 each
    float* y1  = y0 + 4 * N1;
    float* y2  = y1 + 4 * N1;
    float* y3  = y2 + 4 * N1;
    float* x1b = (float*)base + 16 * N1;                  // [66.4MB, 132.8MB)
    float* x2 = (float*)base;                             // after y dead: 32*N2 f32
    float* z0 = x2 + 32 * N2;
    float* z1 = z0 + 8 * N2;
    float* z2 = z1 + 8 * N2;
    float* z3 = z2 + 8 * N2;                              // ends at 33.2MB < x1b start

    float* out = (float*)d_out;   // reference output dtype is float32

    // 1. zero volume + winner (contiguous)
    kz_zero16<<<ZCHUNKS / 256, 256, 0, stream>>>((uint4*)base, ZCHUNKS);

    // 2. deterministic last-write-wins scatter
    kz_scatter_win  <<<NPIX / 256, 256, 0, stream>>>(depth, winner);
    kz_scatter_write<<<NPIX / 256, 256, 0, stream>>>(depth, winner, feat, segu);

    // 3. avg-pool hole-fill, separable, per 4-ch group, in-place
    for (int g = 0; g < 3; ++g) {
        u16* gb = segu + (size_t)g * GRP_U16;
        kz_sumwI<<<(V / 2) / 256, 256, 0, stream>>>(gb, tmpu);
        kz_fillI<<<(V / 2) / 256, 256, 0, stream>>>(gb, tmpu);
    }

    // 4. downsample 1 -> x1 f32 [16][N1]
    kz_ds1<<<N1 / 256, 256, 0, stream>>>(segu, w_ds1, x1);

    // 5. bottleneck 1 (ch16, mid4, spatial 120x72x120)
    kz_pw<16, 4, false><<<N1 / 256, 256, 0, stream>>>(x1, b1_win, nullptr, y0, N1);
    kz_bconv<4, 1, 3, 3, 0><<<N1 / 256, 256, 0, stream>>>(y0, b1w133, b1b133, nullptr, nullptr, y1, D1, H1, W1, N1);
    kz_bconv<4, 3, 3, 1, 1><<<N1 / 256, 256, 0, stream>>>(y1, b1w331, b1b331, y1, nullptr, y2, D1, H1, W1, N1);
    kz_bconv<4, 3, 1, 3, 2><<<N1 / 256, 256, 0, stream>>>(y2, b1w313, b1b313, y2, y1, y3, D1, H1, W1, N1);
    kz_pw<4, 16, true><<<N1 / 256, 256, 0, stream>>>(y3, b1wout, x1, x1b, N1);

    // 6. downsample 2 -> x2 f32 [32][N2]
    kz_ds2<<<(N2 + 255) / 256, 256, 0, stream>>>(x1b, w_ds2, x2);

    // 7. bottleneck 2 (ch32, mid8, spatial 60x36x60) -> f32 d_out
    kz_pw<32, 8, false><<<(N2 + 255) / 256, 256, 0, stream>>>(x2, b2_win, nullptr, z0, N2);
    kz_bconv<8, 1, 3, 3, 0><<<(N2 + 255) / 256, 256, 0, stream>>>(z0, b2w133, b2b133, nullptr, nullptr, z1, D2, H2, W2, N2);
    kz_bconv<8, 3, 3, 1, 1><<<(N2 + 255) / 256, 256, 0, stream>>>(z1, b2w331, b2b331, z1, nullptr, z2, D2, H2, W2, N2);
    kz_bconv<8, 3, 1, 3, 2><<<(N2 + 255) / 256, 256, 0, stream>>>(z2, b2w313, b2b313, z2, z1, z3, D2, H2, W2, N2);
    kz_pw<8, 32, true><<<(N2 + 255) / 256, 256, 0, stream>>>(z3, b2wout, x2, out, N2);

    (void)in_sizes; (void)n_in; (void)out_size; (void)ws_size;
}